// Round 7
// baseline (156.181 us; speedup 1.0000x reference)
//
#include <hip/hip_runtime.h>

#define NB 8
#define N1 2048
#define N2 1152
#define KD 1024
#define BM 256
#define BN 144
#define BNP 145     // padded epilogue stride
#define BK 128      // R16: K-step doubled -> 8 iters, half the sync points
#define BUFB 51200  // one staging buffer: 50 chunks x 1 KB (32 A + 18 B)
#define NBUF 3      // triple buffer -> counted vmcnt, 2 phases of slack (T4)

typedef __attribute__((ext_vector_type(4))) float f32x4;
typedef __attribute__((ext_vector_type(2))) long i64x2;

__device__ __forceinline__ unsigned pack4_fp8(f32x4 v) {
  int t = __builtin_amdgcn_cvt_pk_fp8_f32(v.x, v.y, 0, false);
  t = __builtin_amdgcn_cvt_pk_fp8_f32(v.z, v.w, t, true);
  return (unsigned)t;
}

__device__ __forceinline__ void async_copy16(const void* g, void* l) {
  __builtin_amdgcn_global_load_lds(
      (const __attribute__((address_space(1))) unsigned int*)g,
      (__attribute__((address_space(3))) unsigned int*)l, 16, 0, 0);
}

// convert: R4-verbatim (passed, absmax 0). ONE wave per row; wave-private LDS
// permute -> lgkmcnt(0) only, no block barrier. XCD-aligned: bid&7 = batch,
// fp8 writes stay hot in that XCD's 4 MB L2 for dist (R8-verified).
__global__ __launch_bounds__(256) void convert_kernel(
    const float* __restrict__ x1, const float* __restrict__ x2,
    unsigned char* __restrict__ x1q, unsigned char* __restrict__ x2q,
    float* __restrict__ sq1, float* __restrict__ sq2,
    float* __restrict__ out) {
  __shared__ __align__(16) unsigned char lds[4096];
  if (blockIdx.x == 0 && threadIdx.x == 0) *out = 0.f;  // replaces memset
  int wave = threadIdx.x >> 6, lane = threadIdx.x & 63;
  int bid = blockIdx.x;
  int b = bid & 7;          // batch -> XCD
  int idx = bid >> 3;       // 0..799 within batch
  const float* src;
  unsigned char* dst;
  float* sqp;
  if (idx < N1 / 4) {
    int row = b * N1 + idx * 4 + wave;
    src = x1 + (size_t)row * KD;
    dst = x1q + (size_t)row * KD;
    sqp = sq1 + row;
  } else {
    int row = b * N2 + (idx - N1 / 4) * 4 + wave;
    src = x2 + (size_t)row * KD;
    dst = x2q + (size_t)row * KD;
    sqp = sq2 + row;
  }
  const f32x4* s4 = (const f32x4*)src;
  int r = 4 * (lane & 15);
  int q = (r & 31) >> 3;
  int h = r >> 5;
  int pos = (lane >> 4) * 64 + q * 16 + h * 8 + (r & 7);
  unsigned char* my = lds + wave * 1024;
  float s = 0.f;
#pragma unroll
  for (int i = 0; i < 4; ++i) {
    f32x4 v = __builtin_nontemporal_load(&s4[i * 64 + lane]);
    *(unsigned*)(my + i * 256 + pos) = pack4_fp8(v);
    s += v.x * v.x + v.y * v.y + v.z * v.z + v.w * v.w;
  }
  // wave-private LDS, intra-wave lane exchange only: no block barrier needed
  asm volatile("s_waitcnt lgkmcnt(0)" ::: "memory");
  ((uint4*)dst)[lane] = *(const uint4*)(my + lane * 16);
#pragma unroll
  for (int off = 32; off > 0; off >>= 1) s += __shfl_down(s, off);
  if (lane == 0) *sqp = s;
}

// dist R16: BK=128 -> 8 K-iters (was 16): HALF the sync points (R6 showed
// per-iter instr placement is not the slack; R5's accounting says every
// pipe but MFMA has >=2x margin -> the ~41% gap off the 18.9us MFMA floor
// is per-iter sync cost x16 + epilogue). 8-wave/512-thr blocks,
// __launch_bounds__(512,2): VGPR cap 256 (NOT R5's fatal 128 — acc is now
// acc[2][9]=72 AGPR, ~160 total regs). LDS tribuf 3x50KB=150KB -> 1
// block/CU, 8 waves/CU = 2/SIMD (same TLP as R3's 2x4-wave). Single-pass
// epilogue: eps 256x145x4 = 148.5KB <= 150KB -> 2 barriers (was 4).
// Buffer = 50 x 1KB chunks: A chunk = rc*2+kb (rc=row/16, kb=k-64-block),
// B chunk = 32+rc*2+kb. Inside a chunk: unchanged 16 rows x 64 fp8,
// XOR swizzle (slot ^ (row>>1)&3), k-permuted 16B groups (verified R2-R9).
// Staging UNIFORM 8 loads/wave: chunks 6w..6w+5 (waves 0..7 -> 0..47) +
// chunks 48,49 by ALL waves redundantly (identical-value writes, benign).
// vmcnt: prologue 2 stages = 16 outstanding; per-iter lgkmcnt(0)+vmcnt(8)
// drains EXACTLY stage(cur) (oldest 8, in-order) BEFORE s_barrier => after
// barrier buf[cur] staged by all waves, buf[cur+2] reader-free (R3-proven
// skeleton); tile i's loads get TWO compute phases of slack; peel vmcnt(0).
// CRITICAL: every loop touching acc[][] FULLY UNROLLED (runtime index =
// scratch; tripwire: dist WRITE_SIZE must stay ~0 — R5's spill was 7.2MB).
// Grid 512 @ 1 block/CU (2 rounds, pipelined). b = bid&7 -> batch b on XCD
// b (fp8 L2-hot from convert).
__global__ __launch_bounds__(512, 2) void dist_kernel(
    const unsigned char* __restrict__ x1q, const unsigned char* __restrict__ x2q,
    const float* __restrict__ sq1, const float* __restrict__ sq2,
    float* __restrict__ out) {
  __shared__ __align__(16) char smem[NBUF * BUFB];  // 153600 <= 160K/CU

  const int tid = threadIdx.x;
  const int wave = tid >> 6, lane = tid & 63;  // wave 0..7
  const int bid = blockIdx.x;
  const int b = bid & 7;          // batch -> XCD
  const int bm = (bid >> 3) & 7;  // fastest: A streams, B-tile L2-hot
  const int bn = bid >> 6;

  const unsigned char* Ag = x1q + ((size_t)b * N1 + bm * BM) * KD;
  const unsigned char* Bg = x2q + ((size_t)b * N2 + bn * BN) * KD;

  // staging: lane -> (row lr, 16B slot sl), fetch the swizzled global group
  const int lr = lane >> 2, sl = lane & 3;
  const int goff = (sl ^ ((lr >> 1) & 3)) * 16;

  // fragments: lane (fr, quad) reads swizzled slot -> global 16B group `quad`
  const int quad = lane >> 4, fr = lane & 15;
  const int fslot = (fr * 4 + (quad ^ ((fr >> 1) & 3))) * 16;

  f32x4 acc[2][9];
#pragma unroll
  for (int i = 0; i < 2; ++i)
#pragma unroll
    for (int j = 0; j < 9; ++j) {
      f32x4 z = {0.f, 0.f, 0.f, 0.f};
      acc[i][j] = z;
    }

  // stage(k0): 50 chunks. A: chunk rc*2+kb (rows rc*16.., k k0+kb*64..).
  // B: chunk 32+rc*2+kb. UNIFORM 8 VMEM/wave: 6w..6w+5 + 48,49 by all.
  auto stage = [&](int buf, int k0) {
    char* base = smem + buf * BUFB;
#pragma unroll
    for (int t = 0; t < 6; ++t) {
      int j = wave * 6 + t;
      const unsigned char* g;
      if (j < 32) {
        int rc = j >> 1, kb = j & 1;
        g = Ag + (size_t)(rc * 16 + lr) * KD + k0 + kb * 64 + goff;
      } else {
        int jj = j - 32;
        int rc = jj >> 1, kb = jj & 1;
        g = Bg + (size_t)(rc * 16 + lr) * KD + k0 + kb * 64 + goff;
      }
      async_copy16(g, base + j * 1024 + lane * 16);
    }
    // chunks 48,49 = B rows 128..143 (rc=8), kb=0,1: staged by ALL 8 waves
    async_copy16(Bg + (size_t)(128 + lr) * KD + k0 + goff,
                 base + 48 * 1024 + lane * 16);
    async_copy16(Bg + (size_t)(128 + lr) * KD + k0 + 64 + goff,
                 base + 49 * 1024 + lane * 16);
  };

#define KBODY(cbp, do_stage, knext)                                           \
  {                                                                           \
    const char* cb = (cbp);                                                   \
    if (do_stage) {                                                           \
      int b2 = cur + 2;                                                       \
      if (b2 >= NBUF) b2 -= NBUF;                                             \
      stage(b2, (knext)*BK);                                                  \
    }                                                                         \
    _Pragma("unroll") for (int kb = 0; kb < 2; ++kb) {                        \
      i64x2 a0 = *(const i64x2*)(cb + ((wave * 2 + 0) * 2 + kb) * 1024 + fslot); \
      i64x2 a1 = *(const i64x2*)(cb + ((wave * 2 + 1) * 2 + kb) * 1024 + fslot); \
      _Pragma("unroll") for (int tn = 0; tn < 9; ++tn) {                      \
        i64x2 bf = *(const i64x2*)(cb + (32 + tn * 2 + kb) * 1024 + fslot);   \
        acc[0][tn] = __builtin_amdgcn_mfma_f32_16x16x32_fp8_fp8(              \
            a0.x, bf.x, acc[0][tn], 0, 0, 0);                                 \
        acc[0][tn] = __builtin_amdgcn_mfma_f32_16x16x32_fp8_fp8(              \
            a0.y, bf.y, acc[0][tn], 0, 0, 0);                                 \
        acc[1][tn] = __builtin_amdgcn_mfma_f32_16x16x32_fp8_fp8(              \
            a1.x, bf.x, acc[1][tn], 0, 0, 0);                                 \
        acc[1][tn] = __builtin_amdgcn_mfma_f32_16x16x32_fp8_fp8(              \
            a1.y, bf.y, acc[1][tn], 0, 0, 0);                                 \
      }                                                                       \
    }                                                                         \
  }

  stage(0, 0);    // tiles 0,1 in flight (16 VMEM/wave)
  stage(1, BK);

  int cur = 0;
  for (int i = 0; i < 7; ++i) {
    // own prior ds_reads done + own stage(cur) done (in-order vmcnt), THEN
    // barrier => cross-wave: buf[cur] staged, overwrite target reader-free
    asm volatile("s_waitcnt lgkmcnt(0)" ::: "memory");
    asm volatile("s_waitcnt vmcnt(8)" ::: "memory");
    __builtin_amdgcn_s_barrier();
    __builtin_amdgcn_sched_barrier(0);
    KBODY(smem + cur * BUFB, (i < 6), i + 2);
    ++cur;
    if (cur == NBUF) cur = 0;
  }
  // peeled last iter (tile 7, buffer 1): full drain allowed once
  asm volatile("s_waitcnt lgkmcnt(0)" ::: "memory");
  asm volatile("s_waitcnt vmcnt(0)" ::: "memory");
  __builtin_amdgcn_s_barrier();
  __builtin_amdgcn_sched_barrier(0);
  KBODY(smem + cur * BUFB, false, 0);

  // ---- epilogue: d = sq1 + sq2 - 2*cross, min over 9-col groups, sum ----
  // SINGLE pass: eps = 256 rows x BNP f32 = 148480 B <= 153600 LDS.
  float s2[9];
#pragma unroll
  for (int tn = 0; tn < 9; ++tn)
    s2[tn] = sq2[(size_t)b * N2 + bn * BN + tn * 16 + fr];

  float s1v[2][4];
#pragma unroll
  for (int tm = 0; tm < 2; ++tm)
#pragma unroll
    for (int rr = 0; rr < 4; ++rr)
      s1v[tm][rr] =
          sq1[(size_t)b * N1 + bm * BM + wave * 32 + tm * 16 + quad * 4 + rr];

  float* eps = (float*)smem;
  float local = 0.f;
  __syncthreads();  // all waves done reading K-loop LDS
  // D layout (16x16x32, dtype-independent): col = lane&15 (x2 row),
  // row = quad*4 + reg (x1 row). Wave's rows: wave*32 + tm*16 + quad*4 + rr.
#pragma unroll
  for (int tm = 0; tm < 2; ++tm)
#pragma unroll
    for (int tn = 0; tn < 9; ++tn)
#pragma unroll
      for (int rr = 0; rr < 4; ++rr)
        eps[(wave * 32 + tm * 16 + quad * 4 + rr) * BNP + tn * 16 + fr] =
            s1v[tm][rr] + s2[tn] - 2.0f * acc[tm][tn][rr];
  __syncthreads();
  // 256 rows x 16 groups = 4096 groups, 8 per thread (512 threads)
#pragma unroll
  for (int qq = 0; qq < 8; ++qq) {
    int g = tid + qq * 512;
    int row = g >> 4, grp = g & 15;
    const float* pp = eps + row * BNP + grp * 9;
    float mn = pp[0];
#pragma unroll
    for (int jj = 1; jj < 9; ++jj) mn = fminf(mn, pp[jj]);
    local += mn;
  }

#pragma unroll
  for (int off = 32; off > 0; off >>= 1) local += __shfl_down(local, off);
  __syncthreads();
  if (lane == 0) eps[wave] = local;
  __syncthreads();
  if (tid == 0) {
    float s = 0.f;
#pragma unroll
    for (int w = 0; w < 8; ++w) s += eps[w];
    // total group count = 8 * 2048 * 1152 / 9 = 2097152
    atomicAdd(out, s * (1.0f / 2097152.0f));
  }
}

extern "C" void kernel_launch(void* const* d_in, const int* in_sizes, int n_in,
                              void* d_out, int out_size, void* d_ws, size_t ws_size,
                              hipStream_t stream) {
  const float* x1 = (const float*)d_in[0];
  const float* x2 = (const float*)d_in[1];
  char* ws = (char*)d_ws;
  const size_t x1q_bytes = (size_t)NB * N1 * KD;  // 16777216
  const size_t x2q_bytes = (size_t)NB * N2 * KD;  // 9437184
  unsigned char* x1q = (unsigned char*)ws;
  unsigned char* x2q = (unsigned char*)(ws + x1q_bytes);
  float* sq1 = (float*)(ws + x1q_bytes + x2q_bytes);
  float* sq2 = (float*)(ws + x1q_bytes + x2q_bytes + (size_t)NB * N1 * 4);

  convert_kernel<<<NB * (N1 / 4 + N2 / 4), 256, 0, stream>>>(x1, x2, x1q, x2q,
                                                             sq1, sq2,
                                                             (float*)d_out);
  dist_kernel<<<NB * (N1 / BM) * (N2 / BN), 512, 0, stream>>>(x1q, x2q, sq1, sq2,
                                                              (float*)d_out);
}

// Round 8
// 150.725 us; speedup vs baseline: 1.0362x; 1.0362x over previous
//
#include <hip/hip_runtime.h>

#define NB 8
#define N1 2048
#define N2 1152
#define KD 1024
#define BM 256
#define BN 144
#define BNP 145     // padded epilogue stride
#define BUFB 25600  // one staging buffer: 25 chunks x 1 KB (16 A + 9 B)
#define NBUF 3      // triple buffer -> counted vmcnt, no drain in loop (R3 +5us)

typedef __attribute__((ext_vector_type(4))) float f32x4;
typedef __attribute__((ext_vector_type(2))) long i64x2;

__device__ __forceinline__ unsigned pack4_fp8(f32x4 v) {
  int t = __builtin_amdgcn_cvt_pk_fp8_f32(v.x, v.y, 0, false);
  t = __builtin_amdgcn_cvt_pk_fp8_f32(v.z, v.w, t, true);
  return (unsigned)t;
}

__device__ __forceinline__ void async_copy16(const void* g, void* l) {
  __builtin_amdgcn_global_load_lds(
      (const __attribute__((address_space(1))) unsigned int*)g,
      (__attribute__((address_space(3))) unsigned int*)l, 16, 0, 0);
}

// ===== R17: EXACT REVERT to the R3 champion (150.7 us, absmax 0) =====
// Ledger of everything tried on top of R3 (all reverted here):
//   R4  setprio(T5) + convert-barrier-drop      -> null (151.4)
//   R5  8-wave (512,4): 128-reg cap SPILLED      -> -10 (160.9, 7.2MB scratch)
//   R6  reorder ds_reads first + 2-pass epilogue -> null/neg (153.0)
//   R7  BK=128, 1 blk/CU: lost cross-block overlap -> -5.5 (156.2)
// Conclusion: R3's structure (tribuf + counted vmcnt + 2 blocks/CU cross-
// block overlap) is the local optimum for this geometry; remaining slack is
// distributed (ramp/tail/barrier skew) and only reachable via a full 8-phase
// rebuild (new race surface, single-run validation -> poor EV).

// convert: ONE wave per row. XCD-aligned: bid&7 = batch, so batch b's rows
// convert on XCD b and the fp8 writes (3.3 MB/batch) stay hot in that XCD's
// 4 MB L2 for dist_kernel (R8-verified: FETCH 12.9 MB vs 26 MB compulsory).
// Source fp32 reads NONTEMPORAL so the stream doesn't evict the fp8 lines.
// fp8 pack + k-block permutation staged through LDS, written out as
// coalesced uint4. Permuted layout per 64-value k-block: 16B group q holds
// k=[q*8..q*8+7] ++ [32+q*8..32+q*8+7] -> one b128 LDS read = both k-half
// MFMA fragments.
__global__ __launch_bounds__(256) void convert_kernel(
    const float* __restrict__ x1, const float* __restrict__ x2,
    unsigned char* __restrict__ x1q, unsigned char* __restrict__ x2q,
    float* __restrict__ sq1, float* __restrict__ sq2,
    float* __restrict__ out) {
  __shared__ __align__(16) unsigned char lds[4096];
  if (blockIdx.x == 0 && threadIdx.x == 0) *out = 0.f;  // replaces memset
  int wave = threadIdx.x >> 6, lane = threadIdx.x & 63;
  int bid = blockIdx.x;
  int b = bid & 7;          // batch -> XCD
  int idx = bid >> 3;       // 0..799 within batch
  const float* src;
  unsigned char* dst;
  float* sqp;
  if (idx < N1 / 4) {
    int row = b * N1 + idx * 4 + wave;
    src = x1 + (size_t)row * KD;
    dst = x1q + (size_t)row * KD;
    sqp = sq1 + row;
  } else {
    int row = b * N2 + (idx - N1 / 4) * 4 + wave;
    src = x2 + (size_t)row * KD;
    dst = x2q + (size_t)row * KD;
    sqp = sq2 + row;
  }
  const f32x4* s4 = (const f32x4*)src;
  int r = 4 * (lane & 15);
  int q = (r & 31) >> 3;
  int h = r >> 5;
  int pos = (lane >> 4) * 64 + q * 16 + h * 8 + (r & 7);
  unsigned char* my = lds + wave * 1024;
  float s = 0.f;
#pragma unroll
  for (int i = 0; i < 4; ++i) {
    f32x4 v = __builtin_nontemporal_load(&s4[i * 64 + lane]);
    *(unsigned*)(my + i * 256 + pos) = pack4_fp8(v);
    s += v.x * v.x + v.y * v.y + v.z * v.z + v.w * v.w;
  }
  __syncthreads();  // cross-lane LDS visibility (R3-exact)
  ((uint4*)dst)[lane] = *(const uint4*)(my + lane * 16);
#pragma unroll
  for (int off = 32; off > 0; off >>= 1) s += __shfl_down(s, off);
  if (lane == 0) *sqp = s;
}

// dist (R3-exact): fp8 distance + group-min(9) + mean — BM=256, 4-wave,
// TRIPLE-BUFFER + counted vmcnt (T4). Per-iter sync =
// lgkmcnt(0)+vmcnt(7)+s_barrier -> tile i's loads had TWO compute phases of
// slack; no vmcnt(0) drain in the main loop. Staging UNIFORM 7 loads/wave
// (chunks 6w..6w+5 + chunk 24 by all 4 waves redundantly - identical-value
// LDS writes, benign) so the vmcnt immediate is wave-uniform.
// Sync proof (R3-verified, absmax 0): wave's own ds_reads done (lgkmcnt 0)
// + own stage(cur) done (vmcnt 7, in-order completion) BEFORE s_barrier =>
// after barrier buf[cur] fully staged by ALL waves, and buf[cur+2]
// (overwritten next) has no pending readers. Last iter peeled with vmcnt(0).
// CRITICAL: every loop touching acc[][] FULLY UNROLLED — any runtime index
// scratches accumulators (tripwire: dist WRITE_SIZE must stay ~0; R5's
// spill was 7.2 MB).
// Grid 1D 512 @ 2 blocks/CU — the cross-block overlap IS the latency hiding
// (R7: dropping to 1 blk/CU cost 5.5us). b = bid&7 -> batch b on XCD b.
// LDS chunks 1 KB = 16 rows x 64 fp8, XOR swizzle (slot ^ (row>>1)&3) ->
// conflict-free b128 fragment reads (verified R2-R9).
// LDS 3*25600 = 76800 B (>= 37120 epilogue), x2 blocks/CU = 153.6K <= 160K.
__global__ __launch_bounds__(256, 2) void dist_kernel(
    const unsigned char* __restrict__ x1q, const unsigned char* __restrict__ x2q,
    const float* __restrict__ sq1, const float* __restrict__ sq2,
    float* __restrict__ out) {
  __shared__ __align__(16) char smem[NBUF * BUFB];

  const int tid = threadIdx.x;
  const int wave = tid >> 6, lane = tid & 63;
  const int bid = blockIdx.x;
  const int b = bid & 7;          // batch -> XCD
  const int bm = (bid >> 3) & 7;  // fastest: A streams, B-tile L2-hot
  const int bn = bid >> 6;

  const unsigned char* Ag = x1q + ((size_t)b * N1 + bm * BM) * KD;
  const unsigned char* Bg = x2q + ((size_t)b * N2 + bn * BN) * KD;

  // staging: lane -> (row lr, 16B slot sl), fetch the swizzled global group
  const int lr = lane >> 2, sl = lane & 3;
  const int goff = (sl ^ ((lr >> 1) & 3)) * 16;

  // fragments: lane (fr, quad) reads swizzled slot -> global 16B group `quad`
  const int quad = lane >> 4, fr = lane & 15;
  const int fslot = (fr * 4 + (quad ^ ((fr >> 1) & 3))) * 16;

  f32x4 acc[4][9];
#pragma unroll
  for (int i = 0; i < 4; ++i)
#pragma unroll
    for (int j = 0; j < 9; ++j) {
      f32x4 z = {0.f, 0.f, 0.f, 0.f};
      acc[i][j] = z;
    }

  // stage(k0) into buffer `buf`: 25 chunks (0..15 = A 256 rows, 16..24 = B
  // 144). UNIFORM 7 VMEM/wave: chunks 6w..6w+5 per wave + chunk 24 by all.
  auto stage = [&](int buf, int k0) {
    char* base = smem + buf * BUFB;
#pragma unroll
    for (int t = 0; t < 6; ++t) {
      int j = wave * 6 + t;
      const unsigned char* g;
      if (j < 16)
        g = Ag + (size_t)(j * 16 + lr) * KD + k0 + goff;
      else
        g = Bg + (size_t)((j - 16) * 16 + lr) * KD + k0 + goff;
      async_copy16(g, base + j * 1024 + lane * 16);
    }
    // chunk 24 = B rows 128..143, staged redundantly by all 4 waves
    async_copy16(Bg + (size_t)(128 + lr) * KD + k0 + goff,
                 base + 24 * 1024 + lane * 16);
  };

#define COMPUTE(cbp)                                                          \
  {                                                                           \
    const char* cb = (cbp);                                                   \
    i64x2 a[4];                                                               \
    _Pragma("unroll") for (int tm = 0; tm < 4; ++tm)                          \
        a[tm] = *(const i64x2*)(cb + (wave * 4 + tm) * 1024 + fslot);         \
    _Pragma("unroll") for (int tn = 0; tn < 9; ++tn) {                        \
      i64x2 bf = *(const i64x2*)(cb + 16384 + tn * 1024 + fslot);             \
      _Pragma("unroll") for (int tm = 0; tm < 4; ++tm) {                      \
        acc[tm][tn] = __builtin_amdgcn_mfma_f32_16x16x32_fp8_fp8(             \
            a[tm].x, bf.x, acc[tm][tn], 0, 0, 0);                             \
        acc[tm][tn] = __builtin_amdgcn_mfma_f32_16x16x32_fp8_fp8(             \
            a[tm].y, bf.y, acc[tm][tn], 0, 0, 0);                             \
      }                                                                       \
    }                                                                         \
  }

  stage(0, 0);   // tiles 0,1 in flight (14 VMEM/wave)
  stage(1, 64);

  int cur = 0;
  for (int i = 0; i < 15; ++i) {
    // own prior ds_reads done + own stage(cur) done (in-order vmcnt), THEN
    // barrier => cross-wave: buf[cur] staged, overwrite target reader-free
    asm volatile("s_waitcnt lgkmcnt(0)" ::: "memory");
    asm volatile("s_waitcnt vmcnt(7)" ::: "memory");
    __builtin_amdgcn_s_barrier();
    __builtin_amdgcn_sched_barrier(0);
    if (i < 14) {
      int b2 = cur + 2;
      if (b2 >= NBUF) b2 -= NBUF;
      stage(b2, (i + 2) * 64);
    }
    COMPUTE(smem + cur * BUFB);
    ++cur;
    if (cur == NBUF) cur = 0;
  }
  // peeled last iter (tile 15, buffer 0): full drain allowed once
  asm volatile("s_waitcnt lgkmcnt(0)" ::: "memory");
  asm volatile("s_waitcnt vmcnt(0)" ::: "memory");
  __builtin_amdgcn_s_barrier();
  __builtin_amdgcn_sched_barrier(0);
  COMPUTE(smem + cur * BUFB);

  // ---- epilogue: d = sq1 + sq2 - 2*cross, min over 9-col groups, sum ----
  float s2[9];
#pragma unroll
  for (int tn = 0; tn < 9; ++tn)
    s2[tn] = sq2[(size_t)b * N2 + bn * BN + tn * 16 + fr];

  float s1v[4][4];
#pragma unroll
  for (int tm = 0; tm < 4; ++tm)
#pragma unroll
    for (int rr = 0; rr < 4; ++rr)
      s1v[tm][rr] = sq1[(size_t)b * N1 + bm * BM + wave * 64 + tm * 16 + quad * 4 + rr];

  float* eps = (float*)smem;
  float local = 0.f;
#pragma unroll  // FULL unroll: acc indices must be compile-time constants
  for (int tm = 0; tm < 4; ++tm) {
    __syncthreads();  // K-loop LDS / previous chunk fully consumed
    // D layout (16x16x32, dtype-independent): col = lane&15 (x2 row),
    // row = quad*4 + reg (x1 row). Chunk row = wave*16 + quad*4 + r.
#pragma unroll
    for (int tn = 0; tn < 9; ++tn)
#pragma unroll
      for (int rr = 0; rr < 4; ++rr)
        eps[(wave * 16 + quad * 4 + rr) * BNP + tn * 16 + fr] =
            s1v[tm][rr] + s2[tn] - 2.0f * acc[tm][tn][rr];
    __syncthreads();
    // 64 rows x 16 groups = 1024 groups, 4 per thread
#pragma unroll
    for (int qq = 0; qq < 4; ++qq) {
      int g = tid + qq * 256;
      int row = g >> 4, grp = g & 15;
      const float* p = eps + row * BNP + grp * 9;
      float mn = p[0];
#pragma unroll
      for (int jj = 1; jj < 9; ++jj) mn = fminf(mn, p[jj]);
      local += mn;
    }
  }

#pragma unroll
  for (int off = 32; off > 0; off >>= 1) local += __shfl_down(local, off);
  __syncthreads();
  if (lane == 0) eps[wave] = local;
  __syncthreads();
  if (tid == 0) {
    float s = eps[0] + eps[1] + eps[2] + eps[3];
    // total group count = 8 * 2048 * 1152 / 9 = 2097152
    atomicAdd(out, s * (1.0f / 2097152.0f));
  }
}

extern "C" void kernel_launch(void* const* d_in, const int* in_sizes, int n_in,
                              void* d_out, int out_size, void* d_ws, size_t ws_size,
                              hipStream_t stream) {
  const float* x1 = (const float*)d_in[0];
  const float* x2 = (const float*)d_in[1];
  char* ws = (char*)d_ws;
  const size_t x1q_bytes = (size_t)NB * N1 * KD;  // 16777216
  const size_t x2q_bytes = (size_t)NB * N2 * KD;  // 9437184
  unsigned char* x1q = (unsigned char*)ws;
  unsigned char* x2q = (unsigned char*)(ws + x1q_bytes);
  float* sq1 = (float*)(ws + x1q_bytes + x2q_bytes);
  float* sq2 = (float*)(ws + x1q_bytes + x2q_bytes + (size_t)NB * N1 * 4);

  convert_kernel<<<NB * (N1 / 4 + N2 / 4), 256, 0, stream>>>(x1, x2, x1q, x2q,
                                                             sq1, sq2,
                                                             (float*)d_out);
  dist_kernel<<<NB * (N1 / BM) * (N2 / BN), 256, 0, stream>>>(x1q, x2q, sq1, sq2,
                                                              (float*)d_out);
}